// Round 3
// baseline (335.087 us; speedup 1.0000x reference)
//
#include <hip/hip_runtime.h>

#define NN   10000
#define INC  512
#define HID  512
#define OUTC 256

__global__ void k_zero_int(int* __restrict__ p, int n) {
  int i = blockIdx.x * blockDim.x + threadIdx.x;
  if (i < n) p[i] = 0;
}

__global__ void k_count(const int* __restrict__ dst, int E, int* __restrict__ cnt) {
  int i = blockIdx.x * blockDim.x + threadIdx.x;
  if (i < E) atomicAdd(&cnt[dst[i]], 1);
}

// single block: exclusive prefix over in-degree counts + dinv = rsqrt(deg+1)
__global__ __launch_bounds__(256) void k_scan(const int* __restrict__ cnt, int n,
                                              int* __restrict__ offs, float* __restrict__ dinv) {
  __shared__ int part[256];
  int t = threadIdx.x;
  int chunk = (n + 255) / 256;
  int lo = t * chunk, hi = min(lo + chunk, n);
  int s = 0;
  for (int i = lo; i < hi; ++i) s += cnt[i];
  part[t] = s;
  __syncthreads();
  for (int d = 1; d < 256; d <<= 1) {
    int v = (t >= d) ? part[t - d] : 0;
    __syncthreads();
    part[t] += v;
    __syncthreads();
  }
  int run = (t == 0) ? 0 : part[t - 1];
  for (int i = lo; i < hi; ++i) {
    offs[i] = run;
    int c = cnt[i];
    run += c;
    dinv[i] = rsqrtf((float)(c + 1));   // +1 self-loop
  }
  if (t == 255) offs[n] = run;
}

__global__ void k_fill(const int* __restrict__ src, const int* __restrict__ dst, int E,
                       const int* __restrict__ offs, int* __restrict__ cur, int* __restrict__ csr) {
  int i = blockIdx.x * blockDim.x + threadIdx.x;
  if (i < E) {
    int d = dst[i];
    int p = atomicAdd(&cur[d], 1);
    csr[offs[d] + p] = src[i];
  }
}

// fp32 vector GEMM: C[M,N] = A[M,K] * B[K,N].  BM=128, BN=64, BK=16, 256 thr, 8x4 micro.
__global__ __launch_bounds__(256) void k_gemm(const float* __restrict__ A, const float* __restrict__ B,
                                              float* __restrict__ C, int M, int N, int K) {
  constexpr int BM = 128, BN = 64, BK = 16;
  __shared__ float As[BK][BM + 4];   // transposed A tile, padded
  __shared__ float Bs[BK][BN];

  int t = threadIdx.x;
  int bm = blockIdx.x * BM;
  int bn = blockIdx.y * BN;

  float acc[8][4];
  #pragma unroll
  for (int i = 0; i < 8; ++i)
    #pragma unroll
    for (int j = 0; j < 4; ++j) acc[i][j] = 0.f;

  int am = (t >> 4) * 4;      // 0..60 (quadrants am, am+64)
  int bt = (t & 15) * 4;      // 0..60

  int ar = t >> 2;            // A staging: row within 64-row pass
  int ak = (t & 3) * 4;       // k-offset of the float4
  int br = t >> 4;            // B staging: k row 0..15
  int bc = (t & 15) * 4;      // col

  for (int k0 = 0; k0 < K; k0 += BK) {
    #pragma unroll
    for (int p = 0; p < 2; ++p) {
      int r = ar + p * 64;
      int grow = bm + r;
      float4 v = make_float4(0.f, 0.f, 0.f, 0.f);
      if (grow < M) v = *(const float4*)&A[(size_t)grow * K + k0 + ak];
      As[ak + 0][r] = v.x; As[ak + 1][r] = v.y; As[ak + 2][r] = v.z; As[ak + 3][r] = v.w;
    }
    *(float4*)&Bs[br][bc] = *(const float4*)&B[(size_t)(k0 + br) * N + bn + bc];
    __syncthreads();

    #pragma unroll
    for (int k = 0; k < BK; ++k) {
      float4 va0 = *(const float4*)&As[k][am];
      float4 va1 = *(const float4*)&As[k][am + 64];
      float4 vb  = *(const float4*)&Bs[k][bt];
      float a8[8] = {va0.x, va0.y, va0.z, va0.w, va1.x, va1.y, va1.z, va1.w};
      float b4[4] = {vb.x, vb.y, vb.z, vb.w};
      #pragma unroll
      for (int mi = 0; mi < 8; ++mi)
        #pragma unroll
        for (int ni = 0; ni < 4; ++ni)
          acc[mi][ni] += a8[mi] * b4[ni];
    }
    __syncthreads();
  }

  #pragma unroll
  for (int mq = 0; mq < 2; ++mq)
    #pragma unroll
    for (int mi = 0; mi < 4; ++mi) {
      int row = bm + mq * 64 + am + mi;
      if (row < M) {
        float4 v = make_float4(acc[mq * 4 + mi][0], acc[mq * 4 + mi][1],
                               acc[mq * 4 + mi][2], acc[mq * 4 + mi][3]);
        *(float4*)&C[(size_t)row * N + bn + bt] = v;
      }
    }
}

// per-node gather aggregation: out[i] = dinv[i]*(sum_in dinv[s]*H[s] + dinv[i]*H[i]) + b  (+relu)
template <int F, bool RELU>
__global__ __launch_bounds__(256) void k_agg(const float* __restrict__ H, const float* __restrict__ dinv,
                                             const int* __restrict__ offs, const int* __restrict__ csr,
                                             const float* __restrict__ bias, float* __restrict__ out) {
  constexpr int FT = F / 4;       // feature threads (float4 each)
  constexpr int EG = 256 / FT;    // edge-parallel groups
  __shared__ float red[256][4];
  int node = blockIdx.x;
  int t = threadIdx.x;
  int fc = t % FT;
  int eg = t / FT;
  int lo = offs[node], hi = offs[node + 1];
  float ax = 0.f, ay = 0.f, az = 0.f, aw = 0.f;
  for (int j = lo + eg; j < hi; j += EG) {
    int s = csr[j];
    float w = dinv[s];
    const float4 v = *(const float4*)&H[(size_t)s * F + fc * 4];
    ax += w * v.x; ay += w * v.y; az += w * v.z; aw += w * v.w;
  }
  red[t][0] = ax; red[t][1] = ay; red[t][2] = az; red[t][3] = aw;
  __syncthreads();
  if (eg == 0) {
    #pragma unroll
    for (int g = 1; g < EG; ++g) {
      ax += red[g * FT + fc][0];
      ay += red[g * FT + fc][1];
      az += red[g * FT + fc][2];
      aw += red[g * FT + fc][3];
    }
    float wd = dinv[node];
    const float4 sv = *(const float4*)&H[(size_t)node * F + fc * 4];
    float ox = wd * (ax + wd * sv.x) + bias[fc * 4 + 0];
    float oy = wd * (ay + wd * sv.y) + bias[fc * 4 + 1];
    float oz = wd * (az + wd * sv.z) + bias[fc * 4 + 2];
    float ow = wd * (aw + wd * sv.w) + bias[fc * 4 + 3];
    if (RELU) {
      ox = fmaxf(ox, 0.f); oy = fmaxf(oy, 0.f); oz = fmaxf(oz, 0.f); ow = fmaxf(ow, 0.f);
    }
    *(float4*)&out[(size_t)node * F + fc * 4] = make_float4(ox, oy, oz, ow);
  }
}

extern "C" void kernel_launch(void* const* d_in, const int* in_sizes, int n_in,
                              void* d_out, int out_size, void* d_ws, size_t ws_size,
                              hipStream_t stream) {
  (void)n_in; (void)out_size; (void)ws_size;
  const float* x  = (const float*)d_in[0];
  const int*   ei = (const int*)d_in[1];
  const float* W1 = (const float*)d_in[2];
  const float* b1 = (const float*)d_in[3];
  const float* W2 = (const float*)d_in[4];
  const float* b2 = (const float*)d_in[5];
  float* out = (float*)d_out;

  int E = in_sizes[1] / 2;
  const int* src = ei;
  const int* dst = ei + E;

  char* w = (char*)d_ws;
  float* dinv = (float*)(w);                    // 10000 f
  int*   cnt  = (int*)(w + (1 << 16));          // 10000 i
  int*   cur  = (int*)(w + (2 << 16));          // 10000 i
  int*   offs = (int*)(w + (3 << 16));          // 10001 i
  int*   csr  = (int*)(w + (4 << 16));          // 160000 i (ends < 1 MiB)
  float* h1   = (float*)(w + (1ULL << 20));     // 10000x512 f (20.48 MB)
  float* a1   = (float*)(w + 22020096ULL);      // 10000x512 f
  float* h2   = h1;                             // reuse h1's storage (dead after agg1)

  k_zero_int<<<(NN + 255) / 256, 256, 0, stream>>>(cnt, NN);
  k_zero_int<<<(NN + 255) / 256, 256, 0, stream>>>(cur, NN);
  k_count<<<(E + 255) / 256, 256, 0, stream>>>(dst, E, cnt);
  k_scan<<<1, 256, 0, stream>>>(cnt, NN, offs, dinv);
  k_fill<<<(E + 255) / 256, 256, 0, stream>>>(src, dst, E, offs, cur, csr);

  dim3 g1((NN + 127) / 128, HID / 64);
  k_gemm<<<g1, 256, 0, stream>>>(x, W1, h1, NN, HID, INC);
  k_agg<512, true><<<NN, 256, 0, stream>>>(h1, dinv, offs, csr, b1, a1);

  dim3 g2((NN + 127) / 128, OUTC / 64);
  k_gemm<<<g2, 256, 0, stream>>>(a1, W2, h2, NN, OUTC, HID);
  k_agg<256, false><<<NN, 256, 0, stream>>>(h2, dinv, offs, csr, b2, out);
}

// Round 11
// 258.110 us; speedup vs baseline: 1.2982x; 1.2982x over previous
//
#include <hip/hip_runtime.h>

#define NN   10000

typedef float f32x4 __attribute__((ext_vector_type(4)));
typedef short s16x8 __attribute__((ext_vector_type(8)));
typedef short s16x4 __attribute__((ext_vector_type(4)));

__device__ __forceinline__ unsigned int f2bf(float f) {
  unsigned int u = __float_as_uint(f);
  return (u + 0x7fffu + ((u >> 16) & 1u)) >> 16;   // RNE
}
__device__ __forceinline__ float bf2f(unsigned int h) {
  return __uint_as_float(h << 16);
}

__global__ void k_zero_int(int* __restrict__ p, int n) {
  int i = blockIdx.x * blockDim.x + threadIdx.x;
  if (i < n) p[i] = 0;
}

__global__ void k_count(const int* __restrict__ dst, int E, int* __restrict__ cnt) {
  int i = blockIdx.x * blockDim.x + threadIdx.x;
  if (i < E) atomicAdd(&cnt[dst[i]], 1);
}

__global__ __launch_bounds__(256) void k_scan(const int* __restrict__ cnt, int n,
                                              int* __restrict__ offs, float* __restrict__ dinv) {
  __shared__ int part[256];
  int t = threadIdx.x;
  int chunk = (n + 255) / 256;
  int lo = t * chunk, hi = min(lo + chunk, n);
  int s = 0;
  for (int i = lo; i < hi; ++i) s += cnt[i];
  part[t] = s;
  __syncthreads();
  for (int d = 1; d < 256; d <<= 1) {
    int v = (t >= d) ? part[t - d] : 0;
    __syncthreads();
    part[t] += v;
    __syncthreads();
  }
  int run = (t == 0) ? 0 : part[t - 1];
  for (int i = lo; i < hi; ++i) {
    offs[i] = run;
    int c = cnt[i];
    run += c;
    dinv[i] = rsqrtf((float)(c + 1));   // +1 self-loop
  }
  if (t == 255) offs[n] = run;
}

__global__ void k_fill(const int* __restrict__ src, const int* __restrict__ dst, int E,
                       const int* __restrict__ offs, int* __restrict__ cur, int* __restrict__ csr) {
  int i = blockIdx.x * blockDim.x + threadIdx.x;
  if (i < E) {
    int d = dst[i];
    int p = atomicAdd(&cur[d], 1);
    csr[offs[d] + p] = src[i];
  }
}

// W [512][N] fp32 -> WT [N][1024] bf16: cols 0..511 = hi(W^T), 512..1023 = lo residual
__global__ void k_convw(const float* __restrict__ W, unsigned short* __restrict__ WT, int N) {
  int i = blockIdx.x * blockDim.x + threadIdx.x;
  if (i >= 512 * N) return;
  int k = i / N, n = i - k * N;
  float f = W[i];
  unsigned int hb = f2bf(f);
  WT[(size_t)n * 1024 + k] = (unsigned short)hb;
  WT[(size_t)n * 1024 + 512 + k] = (unsigned short)f2bf(f - bf2f(hb));
}

// Split-bf16 MFMA GEMM: C[M][N] = A[M][512] * W[512][N]  (3-term split, K''=1536)
// Computes C^T fragments via mfma(Wfrag, Afrag). 64x64 block tile, 4 waves (2x2).
// A hi/lo converted on the fly during staging. WT is [N][1024] (hi|lo).
__global__ __launch_bounds__(256) void k_gemm_mfma(
    const float* __restrict__ A, const unsigned short* __restrict__ WT,
    float* __restrict__ C, int M, int N, int NTN) {
  __shared__ short Wh[64 * 40], Wl[64 * 40], Ahs[64 * 40], Als[64 * 40];

  // bijective XCD-chunk swizzle (m204 form)
  int nwg = gridDim.x;
  int q = nwg >> 3, r = nwg & 7;
  int xcd = blockIdx.x & 7, idx = blockIdx.x >> 3;
  int swz = (xcd < r ? xcd * (q + 1) : r * (q + 1) + (xcd - r) * q) + idx;
  int bn = (swz % NTN) * 64;
  int bm = (swz / NTN) * 64;

  int t = threadIdx.x;
  int wid = t >> 6, lane = t & 63;
  int wn = wid & 1, wm = wid >> 1;     // wave tile: 32n x 32m
  int lr = lane & 15, lg = lane >> 4;

  int wrow = t >> 2, kg8 = (t & 3) * 8;   // W staging: 64 rows x 32k (16B each)
  int arow = t >> 3, kc4 = (t & 7) * 4;   // A staging: 32 rows x 8 float4 chunks, 2 passes

  f32x4 acc[2][2];
  #pragma unroll
  for (int i = 0; i < 2; ++i)
    #pragma unroll
    for (int j = 0; j < 2; ++j) acc[i][j] = (f32x4){0.f, 0.f, 0.f, 0.f};

  const unsigned short* wbase = WT + (size_t)(bn + wrow) * 1024;

  for (int kk = 0; kk < 512; kk += 32) {
    __syncthreads();
    // stage W hi & lo tiles (bf16, pre-transposed: rows = n, contiguous k)
    *(s16x8*)&Wh[wrow * 40 + kg8] = *(const s16x8*)&wbase[kk + kg8];
    *(s16x8*)&Wl[wrow * 40 + kg8] = *(const s16x8*)&wbase[512 + kk + kg8];
    // stage A tile, converting fp32 -> bf16 hi + lo residual
    #pragma unroll
    for (int p = 0; p < 2; ++p) {
      int row = arow + p * 32;
      int grow = bm + row;
      float4 v = make_float4(0.f, 0.f, 0.f, 0.f);
      if (grow < M) v = *(const float4*)&A[(size_t)grow * 512 + kk + kc4];
      float fs[4] = {v.x, v.y, v.z, v.w};
      s16x4 hv, lv;
      #pragma unroll
      for (int j = 0; j < 4; ++j) {
        unsigned int hb = f2bf(fs[j]);
        hv[j] = (short)hb;
        lv[j] = (short)f2bf(fs[j] - bf2f(hb));
      }
      *(s16x4*)&Ahs[row * 40 + kc4] = hv;
      *(s16x4*)&Als[row * 40 + kc4] = lv;
    }
    __syncthreads();

    // fragment loads: contiguous 8 bf16 in k per lane (row = lane&15, k = 8*(lane>>4)+j)
    s16x8 fwh[2], fwl[2], fah[2], fal[2];
    #pragma unroll
    for (int i = 0; i < 2; ++i) {
      int nr = wn * 32 + i * 16 + lr;
      int mr = wm * 32 + i * 16 + lr;
      fwh[i] = *(const s16x8*)&Wh[nr * 40 + lg * 8];
      fwl[i] = *(const s16x8*)&Wl[nr * 40 + lg * 8];
      fah[i] = *(const s16x8*)&Ahs[mr * 40 + lg * 8];
      fal[i] = *(const s16x8*)&Als[mr * 40 + lg * 8];
    }
    #pragma unroll
    for (int mi = 0; mi < 2; ++mi)
      #pragma unroll
      for (int ni = 0; ni < 2; ++ni) {
        acc[mi][ni] = __builtin_amdgcn_mfma_f32_16x16x32_bf16(fwh[ni], fah[mi], acc[mi][ni], 0, 0, 0);
        acc[mi][ni] = __builtin_amdgcn_mfma_f32_16x16x32_bf16(fwl[ni], fah[mi], acc[mi][ni], 0, 0, 0);
        acc[mi][ni] = __builtin_amdgcn_mfma_f32_16x16x32_bf16(fwh[ni], fal[mi], acc[mi][ni], 0, 0, 0);
      }
  }

  // D holds C^T tile: row-role = n, col-role = m. Lane: m = base_m + (lane&15),
  // n = base_n + 4*(lane>>4) + reg  -> one float4 store per fragment.
  #pragma unroll
  for (int mi = 0; mi < 2; ++mi) {
    int m = bm + wm * 32 + mi * 16 + lr;
    if (m < M) {
      #pragma unroll
      for (int ni = 0; ni < 2; ++ni) {
        int n0 = bn + wn * 32 + ni * 16 + lg * 4;
        *(f32x4*)&C[(size_t)m * N + n0] = acc[mi][ni];
      }
    }
  }
}

// per-node gather aggregation: out[i] = dinv[i]*(sum_in dinv[s]*H[s] + dinv[i]*H[i]) + b  (+relu)
template <int F, bool RELU>
__global__ __launch_bounds__(256) void k_agg(const float* __restrict__ H, const float* __restrict__ dinv,
                                             const int* __restrict__ offs, const int* __restrict__ csr,
                                             const float* __restrict__ bias, float* __restrict__ out) {
  constexpr int FT = F / 4;
  constexpr int EG = 256 / FT;
  __shared__ float red[256][4];
  int node = blockIdx.x;
  int t = threadIdx.x;
  int fc = t % FT;
  int eg = t / FT;
  int lo = offs[node], hi = offs[node + 1];
  float ax = 0.f, ay = 0.f, az = 0.f, aw = 0.f;
  for (int j = lo + eg; j < hi; j += EG) {
    int s = csr[j];
    float w = dinv[s];
    const float4 v = *(const float4*)&H[(size_t)s * F + fc * 4];
    ax += w * v.x; ay += w * v.y; az += w * v.z; aw += w * v.w;
  }
  red[t][0] = ax; red[t][1] = ay; red[t][2] = az; red[t][3] = aw;
  __syncthreads();
  if (eg == 0) {
    #pragma unroll
    for (int g = 1; g < EG; ++g) {
      ax += red[g * FT + fc][0];
      ay += red[g * FT + fc][1];
      az += red[g * FT + fc][2];
      aw += red[g * FT + fc][3];
    }
    float wd = dinv[node];
    const float4 sv = *(const float4*)&H[(size_t)node * F + fc * 4];
    float ox = wd * (ax + wd * sv.x) + bias[fc * 4 + 0];
    float oy = wd * (ay + wd * sv.y) + bias[fc * 4 + 1];
    float oz = wd * (az + wd * sv.z) + bias[fc * 4 + 2];
    float ow = wd * (aw + wd * sv.w) + bias[fc * 4 + 3];
    if (RELU) {
      ox = fmaxf(ox, 0.f); oy = fmaxf(oy, 0.f); oz = fmaxf(oz, 0.f); ow = fmaxf(ow, 0.f);
    }
    *(float4*)&out[(size_t)node * F + fc * 4] = make_float4(ox, oy, oz, ow);
  }
}

extern "C" void kernel_launch(void* const* d_in, const int* in_sizes, int n_in,
                              void* d_out, int out_size, void* d_ws, size_t ws_size,
                              hipStream_t stream) {
  (void)n_in; (void)out_size; (void)ws_size;
  const float* x  = (const float*)d_in[0];
  const int*   ei = (const int*)d_in[1];
  const float* W1 = (const float*)d_in[2];
  const float* b1 = (const float*)d_in[3];
  const float* W2 = (const float*)d_in[4];
  const float* b2 = (const float*)d_in[5];
  float* out = (float*)d_out;

  int E = in_sizes[1] / 2;
  const int* src = ei;
  const int* dst = ei + E;

  char* w = (char*)d_ws;
  float*          dinv = (float*)(w);
  int*            cnt  = (int*)(w + 65536);
  int*            cur  = (int*)(w + 131072);
  int*            offs = (int*)(w + 196608);
  int*            csr  = (int*)(w + 262144);           // 640 KB
  unsigned short* WT1  = (unsigned short*)(w + 1048576);   // 1 MB
  unsigned short* WT2  = (unsigned short*)(w + 2097152);   // 0.5 MB
  float*          h1   = (float*)(w + 3145728);            // 20.48 MB
  float*          a1   = (float*)(w + 23625728ULL);        // 20.48 MB (ends ~42.1 MB)
  float*          h2   = h1;                               // h1 dead after agg1

  k_zero_int<<<(NN + 255) / 256, 256, 0, stream>>>(cnt, NN);
  k_zero_int<<<(NN + 255) / 256, 256, 0, stream>>>(cur, NN);
  k_count<<<(E + 255) / 256, 256, 0, stream>>>(dst, E, cnt);
  k_scan<<<1, 256, 0, stream>>>(cnt, NN, offs, dinv);
  k_fill<<<(E + 255) / 256, 256, 0, stream>>>(src, dst, E, offs, cur, csr);

  k_convw<<<(512 * 512 + 255) / 256, 256, 0, stream>>>(W1, WT1, 512);
  k_convw<<<(512 * 256 + 255) / 256, 256, 0, stream>>>(W2, WT2, 256);

  int ntm = (NN + 63) / 64;   // 157
  k_gemm_mfma<<<8 * ntm, 256, 0, stream>>>(x, WT1, h1, NN, 512, 8);
  k_agg<512, true><<<NN, 256, 0, stream>>>(h1, dinv, offs, csr, b1, a1);
  k_gemm_mfma<<<4 * ntm, 256, 0, stream>>>(a1, WT2, h2, NN, 256, 4);
  k_agg<256, false><<<NN, 256, 0, stream>>>(h2, dinv, offs, csr, b2, out);
}

// Round 13
// 219.419 us; speedup vs baseline: 1.5272x; 1.1763x over previous
//
#include <hip/hip_runtime.h>

#define NN   10000

typedef float f32x4 __attribute__((ext_vector_type(4)));
typedef short s16x8 __attribute__((ext_vector_type(8)));
typedef short s16x4 __attribute__((ext_vector_type(4)));

__device__ __forceinline__ unsigned int f2bf(float f) {
  unsigned int u = __float_as_uint(f);
  return (u + 0x7fffu + ((u >> 16) & 1u)) >> 16;   // RNE
}
__device__ __forceinline__ float bf2f(unsigned int h) {
  return __uint_as_float(h << 16);
}

__global__ void k_zero_int(int* __restrict__ p, int n) {
  int i = blockIdx.x * blockDim.x + threadIdx.x;
  if (i < n) p[i] = 0;
}

__global__ void k_count(const int* __restrict__ dst, int E, int* __restrict__ cnt) {
  int i = blockIdx.x * blockDim.x + threadIdx.x;
  if (i < E) atomicAdd(&cnt[dst[i]], 1);
}

__global__ __launch_bounds__(256) void k_scan(const int* __restrict__ cnt, int n,
                                              int* __restrict__ offs, float* __restrict__ dinv) {
  __shared__ int part[256];
  int t = threadIdx.x;
  int chunk = (n + 255) / 256;
  int lo = t * chunk, hi = min(lo + chunk, n);
  int s = 0;
  for (int i = lo; i < hi; ++i) s += cnt[i];
  part[t] = s;
  __syncthreads();
  for (int d = 1; d < 256; d <<= 1) {
    int v = (t >= d) ? part[t - d] : 0;
    __syncthreads();
    part[t] += v;
    __syncthreads();
  }
  int run = (t == 0) ? 0 : part[t - 1];
  for (int i = lo; i < hi; ++i) {
    offs[i] = run;
    int c = cnt[i];
    run += c;
    dinv[i] = rsqrtf((float)(c + 1));   // +1 self-loop
  }
  if (t == 255) offs[n] = run;
}

__global__ void k_fill(const int* __restrict__ src, const int* __restrict__ dst, int E,
                       const int* __restrict__ offs, int* __restrict__ cur, int* __restrict__ csr) {
  int i = blockIdx.x * blockDim.x + threadIdx.x;
  if (i < E) {
    int d = dst[i];
    int p = atomicAdd(&cur[d], 1);
    csr[offs[d] + p] = src[i];
  }
}

// W [512][N] fp32 -> WT [N][1024] bf16: cols 0..511 = hi(W^T), 512..1023 = lo residual
__global__ void k_convw(const float* __restrict__ W, unsigned short* __restrict__ WT, int N) {
  int i = blockIdx.x * blockDim.x + threadIdx.x;
  if (i >= 512 * N) return;
  int k = i / N, n = i - k * N;
  float f = W[i];
  unsigned int hb = f2bf(f);
  WT[(size_t)n * 1024 + k] = (unsigned short)hb;
  WT[(size_t)n * 1024 + 512 + k] = (unsigned short)f2bf(f - bf2f(hb));
}

// MFMA GEMM, C (bf16) [M][N] = A[M][512] * W[512][N].
// ASPLIT=true:  A fp32, split on the fly -> 3 MFMA terms (AhWh, AhWl, AlWh)
// ASPLIT=false: A already bf16 (exact)   -> 2 MFMA terms (AWh, AWl)
// C^T fragments via mfma(Wfrag, Afrag). 64x64 tile, 4 waves (2x2). WT [N][1024] (hi|lo).
template <bool ASPLIT>
__global__ __launch_bounds__(256) void k_gemm_mfma(
    const void* __restrict__ Ap, const unsigned short* __restrict__ WT,
    unsigned short* __restrict__ C, int M, int N, int NTN) {
  __shared__ short Wh[64 * 40], Wl[64 * 40], Ahs[64 * 40];
  __shared__ short Als[ASPLIT ? 64 * 40 : 8];

  // bijective XCD-chunk swizzle (m204 form)
  int nwg = gridDim.x;
  int q = nwg >> 3, r = nwg & 7;
  int xcd = blockIdx.x & 7, idx = blockIdx.x >> 3;
  int swz = (xcd < r ? xcd * (q + 1) : r * (q + 1) + (xcd - r) * q) + idx;
  int bn = (swz % NTN) * 64;
  int bm = (swz / NTN) * 64;

  int t = threadIdx.x;
  int wid = t >> 6, lane = t & 63;
  int wn = wid & 1, wm = wid >> 1;     // wave tile: 32n x 32m
  int lr = lane & 15, lg = lane >> 4;

  int wrow = t >> 2, kg8 = (t & 3) * 8;   // W staging: 64 rows x 32k (16B each)
  int arow = t >> 3, kc4 = (t & 7) * 4;   // A fp32 staging: 32 rows x 8 float4, 2 passes
  int brow = t >> 2, kb8 = (t & 3) * 8;   // A bf16 staging: 64 rows x 32k (16B each)

  f32x4 acc[2][2];
  #pragma unroll
  for (int i = 0; i < 2; ++i)
    #pragma unroll
    for (int j = 0; j < 2; ++j) acc[i][j] = (f32x4){0.f, 0.f, 0.f, 0.f};

  const unsigned short* wbase = WT + (size_t)(bn + wrow) * 1024;

  for (int kk = 0; kk < 512; kk += 32) {
    __syncthreads();
    // stage W hi & lo tiles (bf16, pre-transposed: rows = n, contiguous k)
    *(s16x8*)&Wh[wrow * 40 + kg8] = *(const s16x8*)&wbase[kk + kg8];
    *(s16x8*)&Wl[wrow * 40 + kg8] = *(const s16x8*)&wbase[512 + kk + kg8];
    if (ASPLIT) {
      // stage A tile from fp32, converting -> bf16 hi + lo residual
      const float* A = (const float*)Ap;
      #pragma unroll
      for (int p = 0; p < 2; ++p) {
        int row = arow + p * 32;
        int grow = bm + row;
        float4 v = make_float4(0.f, 0.f, 0.f, 0.f);
        if (grow < M) v = *(const float4*)&A[(size_t)grow * 512 + kk + kc4];
        float fs[4] = {v.x, v.y, v.z, v.w};
        s16x4 hv, lv;
        #pragma unroll
        for (int j = 0; j < 4; ++j) {
          unsigned int hb = f2bf(fs[j]);
          hv[j] = (short)hb;
          lv[j] = (short)f2bf(fs[j] - bf2f(hb));
        }
        *(s16x4*)&Ahs[row * 40 + kc4] = hv;
        *(s16x4*)&Als[row * 40 + kc4] = lv;
      }
    } else {
      // stage A tile directly from bf16
      const unsigned short* Ab = (const unsigned short*)Ap;
      int grow = bm + brow;
      s16x8 v = (s16x8){0, 0, 0, 0, 0, 0, 0, 0};
      if (grow < M) v = *(const s16x8*)&Ab[(size_t)grow * 512 + kk + kb8];
      *(s16x8*)&Ahs[brow * 40 + kb8] = v;
    }
    __syncthreads();

    // fragment loads: contiguous 8 bf16 in k per lane (row = lane&15, k = 8*(lane>>4)+j)
    s16x8 fwh[2], fwl[2], fah[2], fal[2];
    #pragma unroll
    for (int i = 0; i < 2; ++i) {
      int nr = wn * 32 + i * 16 + lr;
      int mr = wm * 32 + i * 16 + lr;
      fwh[i] = *(const s16x8*)&Wh[nr * 40 + lg * 8];
      fwl[i] = *(const s16x8*)&Wl[nr * 40 + lg * 8];
      fah[i] = *(const s16x8*)&Ahs[mr * 40 + lg * 8];
      if (ASPLIT) fal[i] = *(const s16x8*)&Als[mr * 40 + lg * 8];
    }
    #pragma unroll
    for (int mi = 0; mi < 2; ++mi)
      #pragma unroll
      for (int ni = 0; ni < 2; ++ni) {
        acc[mi][ni] = __builtin_amdgcn_mfma_f32_16x16x32_bf16(fwh[ni], fah[mi], acc[mi][ni], 0, 0, 0);
        acc[mi][ni] = __builtin_amdgcn_mfma_f32_16x16x32_bf16(fwl[ni], fah[mi], acc[mi][ni], 0, 0, 0);
        if (ASPLIT)
          acc[mi][ni] = __builtin_amdgcn_mfma_f32_16x16x32_bf16(fwh[ni], fal[mi], acc[mi][ni], 0, 0, 0);
      }
  }

  // D holds C^T tile: lane m = bm+.. + (lane&15), n = bn+.. + 4*(lane>>4) + reg.
  #pragma unroll
  for (int mi = 0; mi < 2; ++mi) {
    int m = bm + wm * 32 + mi * 16 + lr;
    if (m < M) {
      #pragma unroll
      for (int ni = 0; ni < 2; ++ni) {
        int n0 = bn + wn * 32 + ni * 16 + lg * 4;
        ushort4 cv;
        cv.x = (unsigned short)f2bf(acc[mi][ni][0]);
        cv.y = (unsigned short)f2bf(acc[mi][ni][1]);
        cv.z = (unsigned short)f2bf(acc[mi][ni][2]);
        cv.w = (unsigned short)f2bf(acc[mi][ni][3]);
        *(ushort4*)&C[(size_t)m * N + n0] = cv;
      }
    }
  }
}

// per-node gather aggregation over bf16 H:
// out[i] = dinv[i]*(sum_in dinv[s]*H[s] + dinv[i]*H[i]) + b  (+relu), out bf16 or fp32
template <int F, bool RELU, bool OUTBF16>
__global__ __launch_bounds__(256) void k_agg_bf(
    const unsigned short* __restrict__ H, const float* __restrict__ dinv,
    const int* __restrict__ offs, const int* __restrict__ csr,
    const float* __restrict__ bias, void* __restrict__ outp) {
  constexpr int FT = F / 8;       // feature threads (8 bf16 = 16B each)
  constexpr int EG = 256 / FT;    // edge-parallel groups (4 for F=512, 8 for F=256)
  __shared__ float red[256][8];
  int node = blockIdx.x;
  int t = threadIdx.x;
  int fc = t % FT;
  int eg = t / FT;
  int lo = offs[node], hi = offs[node + 1];
  float a[8];
  #pragma unroll
  for (int j = 0; j < 8; ++j) a[j] = 0.f;
  for (int e = lo + eg; e < hi; e += EG) {
    int s = csr[e];
    float w = dinv[s];
    s16x8 v = *(const s16x8*)&H[(size_t)s * F + fc * 8];
    #pragma unroll
    for (int j = 0; j < 8; ++j) a[j] += w * bf2f((unsigned short)v[j]);
  }
  #pragma unroll
  for (int j = 0; j < 8; ++j) red[t][j] = a[j];
  __syncthreads();
  if (eg == 0) {
    #pragma unroll
    for (int g = 1; g < EG; ++g)
      #pragma unroll
      for (int j = 0; j < 8; ++j) a[j] += red[g * FT + fc][j];
    float wd = dinv[node];
    s16x8 sv = *(const s16x8*)&H[(size_t)node * F + fc * 8];
    float o[8];
    #pragma unroll
    for (int j = 0; j < 8; ++j) {
      o[j] = wd * (a[j] + wd * bf2f((unsigned short)sv[j])) + bias[fc * 8 + j];
      if (RELU) o[j] = fmaxf(o[j], 0.f);
    }
    if (OUTBF16) {
      s16x8 hv;
      #pragma unroll
      for (int j = 0; j < 8; ++j) hv[j] = (short)f2bf(o[j]);
      *(s16x8*)&((unsigned short*)outp)[(size_t)node * F + fc * 8] = hv;
    } else {
      float* op = (float*)outp;
      *(float4*)&op[(size_t)node * F + fc * 8]     = make_float4(o[0], o[1], o[2], o[3]);
      *(float4*)&op[(size_t)node * F + fc * 8 + 4] = make_float4(o[4], o[5], o[6], o[7]);
    }
  }
}

extern "C" void kernel_launch(void* const* d_in, const int* in_sizes, int n_in,
                              void* d_out, int out_size, void* d_ws, size_t ws_size,
                              hipStream_t stream) {
  (void)n_in; (void)out_size; (void)ws_size;
  const float* x  = (const float*)d_in[0];
  const int*   ei = (const int*)d_in[1];
  const float* W1 = (const float*)d_in[2];
  const float* b1 = (const float*)d_in[3];
  const float* W2 = (const float*)d_in[4];
  const float* b2 = (const float*)d_in[5];
  float* out = (float*)d_out;

  int E = in_sizes[1] / 2;
  const int* src = ei;
  const int* dst = ei + E;

  char* w = (char*)d_ws;
  float*          dinv = (float*)(w);
  int*            cnt  = (int*)(w + 65536);
  int*            cur  = (int*)(w + 131072);
  int*            offs = (int*)(w + 196608);
  int*            csr  = (int*)(w + 262144);               // 640 KB
  unsigned short* WT1  = (unsigned short*)(w + 1048576);   // 1 MB
  unsigned short* WT2  = (unsigned short*)(w + 2097152);   // 0.5 MB
  unsigned short* h1   = (unsigned short*)(w + 3145728);   // 10.24 MB (bf16)
  unsigned short* a1   = (unsigned short*)(w + 14680064);  // 10.24 MB (bf16)
  unsigned short* h2   = (unsigned short*)(w + 26214400);  // 5.12 MB (bf16), ends ~31.3 MB

  k_zero_int<<<(NN + 255) / 256, 256, 0, stream>>>(cnt, NN);
  k_zero_int<<<(NN + 255) / 256, 256, 0, stream>>>(cur, NN);
  k_count<<<(E + 255) / 256, 256, 0, stream>>>(dst, E, cnt);
  k_scan<<<1, 256, 0, stream>>>(cnt, NN, offs, dinv);
  k_fill<<<(E + 255) / 256, 256, 0, stream>>>(src, dst, E, offs, cur, csr);

  k_convw<<<(512 * 512 + 255) / 256, 256, 0, stream>>>(W1, WT1, 512);
  k_convw<<<(512 * 256 + 255) / 256, 256, 0, stream>>>(W2, WT2, 256);

  int ntm = (NN + 63) / 64;   // 157
  k_gemm_mfma<true><<<8 * ntm, 256, 0, stream>>>(x, WT1, h1, NN, 512, 8);
  k_agg_bf<512, true, true><<<NN, 256, 0, stream>>>(h1, dinv, offs, csr, b1, a1);
  k_gemm_mfma<false><<<4 * ntm, 256, 0, stream>>>(a1, WT2, h2, NN, 256, 4);
  k_agg_bf<256, false, false><<<NN, 256, 0, stream>>>(h2, dinv, offs, csr, b2, out);
}